// Round 1
// baseline (272.751 us; speedup 1.0000x reference)
//
#include <hip/hip_runtime.h>
#include <math.h>

#define BATCH 32768
#define NCLS 1000
#define NC4  250   // 1000 / 4

// One block per row: vectorized load of x (float4) and t (int4),
// accumulate s_neg = sum exp(x) over t==0, s_pos = sum exp(-x) over t>0,
// reduce across the block, write per-row product to workspace.
__global__ __launch_bounds__(256) void lsep_row_kernel(
    const float* __restrict__ x,
    const int*   __restrict__ t,
    float* __restrict__ row_out) {

    const int row = blockIdx.x;
    const int tid = threadIdx.x;

    const float4* xr = (const float4*)(x + (size_t)row * NCLS);
    const int4*   tr = (const int4*)(t + (size_t)row * NCLS);

    float sn = 0.0f, sp = 0.0f;
    if (tid < NC4) {
        float4 xv = xr[tid];
        int4   tv = tr[tid];
        if (tv.x == 0) sn += __expf(xv.x); else sp += __expf(-xv.x);
        if (tv.y == 0) sn += __expf(xv.y); else sp += __expf(-xv.y);
        if (tv.z == 0) sn += __expf(xv.z); else sp += __expf(-xv.z);
        if (tv.w == 0) sn += __expf(xv.w); else sp += __expf(-xv.w);
    }

    // wave (64-lane) shuffle reduction
    #pragma unroll
    for (int off = 32; off > 0; off >>= 1) {
        sn += __shfl_down(sn, off, 64);
        sp += __shfl_down(sp, off, 64);
    }

    __shared__ float ssn[4], ssp[4];
    const int wave = tid >> 6;
    const int lane = tid & 63;
    if (lane == 0) { ssn[wave] = sn; ssp[wave] = sp; }
    __syncthreads();

    if (tid == 0) {
        float tn = ssn[0] + ssn[1] + ssn[2] + ssn[3];
        float tp = ssp[0] + ssp[1] + ssp[2] + ssp[3];
        row_out[row] = tn * tp;
    }
}

// Single block: sum 32768 per-row products, write log1p(total).
__global__ __launch_bounds__(256) void lsep_reduce_kernel(
    const float* __restrict__ row_out,
    float* __restrict__ out) {

    const int tid = threadIdx.x;
    float v = 0.0f;
    // vectorized grid-stride over 32768 floats (8192 float4)
    const float4* r4 = (const float4*)row_out;
    for (int i = tid; i < BATCH / 4; i += 256) {
        float4 a = r4[i];
        v += a.x + a.y + a.z + a.w;
    }

    #pragma unroll
    for (int off = 32; off > 0; off >>= 1)
        v += __shfl_down(v, off, 64);

    __shared__ float sv[4];
    const int wave = tid >> 6;
    const int lane = tid & 63;
    if (lane == 0) sv[wave] = v;
    __syncthreads();

    if (tid == 0) {
        float total = sv[0] + sv[1] + sv[2] + sv[3];
        out[0] = log1pf(total);
    }
}

extern "C" void kernel_launch(void* const* d_in, const int* in_sizes, int n_in,
                              void* d_out, int out_size, void* d_ws, size_t ws_size,
                              hipStream_t stream) {
    const float* x = (const float*)d_in[0];
    const int*   t = (const int*)d_in[1];
    float* out     = (float*)d_out;
    float* row_ws  = (float*)d_ws;   // BATCH floats = 128 KB

    lsep_row_kernel<<<BATCH, 256, 0, stream>>>(x, t, row_ws);
    lsep_reduce_kernel<<<1, 256, 0, stream>>>(row_ws, out);
}

// Round 2
// 270.074 us; speedup vs baseline: 1.0099x; 1.0099x over previous
//
#include <hip/hip_runtime.h>
#include <math.h>

#define BATCH   32768
#define NCLS    1000
#define NC4     250      // 1000/4 float4 per row
#define NBLOCKS 2048
#define NWAVES  (NBLOCKS * 4)   // 8192 waves, 4 rows per wave

// Persistent wave-per-row kernel. Lane l of a wave loads float4/int4 chunks
// l, l+64, l+128, l+192 of its row (250 chunks -> last pass partial).
// All 8 loads issued before any use -> deep MLP. Shuffle-reduce sn/sp per
// row (no barrier, no LDS), lane0 accumulates sn*sp across the wave's rows,
// one write per wave.
__global__ __launch_bounds__(256) void lsep_row_kernel(
    const float* __restrict__ x,
    const int*   __restrict__ t,
    float* __restrict__ wave_out) {

    const int tid   = threadIdx.x;
    const int lane  = tid & 63;
    const int gwave = blockIdx.x * 4 + (tid >> 6);   // 0..NWAVES-1

    float acc = 0.0f;   // lane 0: running sum of sn*sp over this wave's rows

    #pragma unroll
    for (int r = 0; r < BATCH / NWAVES; ++r) {
        const int row = gwave + r * NWAVES;
        const float4* xr = (const float4*)(x + (size_t)row * NCLS);
        const int4*   tr = (const int4*)(t + (size_t)row * NCLS);

        // stage all loads first (independent -> pipelined)
        float4 xv[4];
        int4   tv[4];
        #pragma unroll
        for (int j = 0; j < 4; ++j) {
            const int idx = lane + 64 * j;
            if (idx < NC4) {
                xv[j] = xr[idx];
                tv[j] = tr[idx];
            }
        }

        float sn = 0.0f, sp = 0.0f;
        #pragma unroll
        for (int j = 0; j < 4; ++j) {
            const int idx = lane + 64 * j;
            if (idx < NC4) {
                {   float e = __expf(xv[j].x); float r1 = __builtin_amdgcn_rcpf(e);
                    if (tv[j].x == 0) sn += e; else sp += r1; }
                {   float e = __expf(xv[j].y); float r1 = __builtin_amdgcn_rcpf(e);
                    if (tv[j].y == 0) sn += e; else sp += r1; }
                {   float e = __expf(xv[j].z); float r1 = __builtin_amdgcn_rcpf(e);
                    if (tv[j].z == 0) sn += e; else sp += r1; }
                {   float e = __expf(xv[j].w); float r1 = __builtin_amdgcn_rcpf(e);
                    if (tv[j].w == 0) sn += e; else sp += r1; }
            }
        }

        // 64-lane shuffle reduction (no barrier)
        #pragma unroll
        for (int off = 32; off > 0; off >>= 1) {
            sn += __shfl_down(sn, off, 64);
            sp += __shfl_down(sp, off, 64);
        }

        if (lane == 0) acc += sn * sp;
    }

    if (lane == 0) wave_out[gwave] = acc;
}

// Single block reduces NWAVES partials: 8 independent float4 loads per
// thread (fully unrolled), shuffle + LDS reduce, log1p.
__global__ __launch_bounds__(256) void lsep_reduce_kernel(
    const float* __restrict__ wave_out,
    float* __restrict__ out) {

    const int tid = threadIdx.x;
    const float4* r4 = (const float4*)wave_out;   // NWAVES/4 = 2048 float4

    float4 a[8];
    #pragma unroll
    for (int j = 0; j < 8; ++j)
        a[j] = r4[tid + 256 * j];

    float v = 0.0f;
    #pragma unroll
    for (int j = 0; j < 8; ++j)
        v += (a[j].x + a[j].y) + (a[j].z + a[j].w);

    #pragma unroll
    for (int off = 32; off > 0; off >>= 1)
        v += __shfl_down(v, off, 64);

    __shared__ float sv[4];
    const int wave = tid >> 6;
    const int lane = tid & 63;
    if (lane == 0) sv[wave] = v;
    __syncthreads();

    if (tid == 0) {
        float total = (sv[0] + sv[1]) + (sv[2] + sv[3]);
        out[0] = log1pf(total);
    }
}

extern "C" void kernel_launch(void* const* d_in, const int* in_sizes, int n_in,
                              void* d_out, int out_size, void* d_ws, size_t ws_size,
                              hipStream_t stream) {
    const float* x = (const float*)d_in[0];
    const int*   t = (const int*)d_in[1];
    float* out     = (float*)d_out;
    float* wave_ws = (float*)d_ws;   // NWAVES floats = 32 KB

    lsep_row_kernel<<<NBLOCKS, 256, 0, stream>>>(x, t, wave_ws);
    lsep_reduce_kernel<<<1, 256, 0, stream>>>(wave_ws, out);
}